// Round 3
// baseline (1352.106 us; speedup 1.0000x reference)
//
#include <hip/hip_runtime.h>
#include <hip/hip_bf16.h>
#include <stdint.h>

#define SEQ      4096
#define BATCH    4
#define HIDDEN   2048
#define CHANNELS 4096
#define MTOT     (BATCH*SEQ)   // 16384

typedef __bf16 bf16;
typedef __bf16 bf16x8 __attribute__((ext_vector_type(8)));
typedef float  f32x4  __attribute__((ext_vector_type(4)));

// async 16B global->LDS (wave-uniform base + lane*16 on LDS side)
#define GLDS16(g, l) __builtin_amdgcn_global_load_lds(                      \
    (const __attribute__((address_space(1))) void*)(g),                     \
    (__attribute__((address_space(3))) void*)(l), 16, 0, 0)

// ---------------------------------------------------------------------------
// fp32 -> bf16 cast, 8 elems/thread (two float4 loads, one 16B store)
// ---------------------------------------------------------------------------
union B8 { uint4 v; bf16 h[8]; };

__global__ __launch_bounds__(256)
void cast_f32_to_bf16(const float* __restrict__ in, bf16* __restrict__ out) {
    const long long i = (long long)blockIdx.x * 256 + threadIdx.x;
    const float4 a = ((const float4*)in)[2 * i];
    const float4 b = ((const float4*)in)[2 * i + 1];
    B8 o;
    o.h[0] = (bf16)a.x; o.h[1] = (bf16)a.y; o.h[2] = (bf16)a.z; o.h[3] = (bf16)a.w;
    o.h[4] = (bf16)b.x; o.h[5] = (bf16)b.y; o.h[6] = (bf16)b.z; o.h[7] = (bf16)b.w;
    *(uint4*)(out + 8 * i) = o.v;
}

// ---------------------------------------------------------------------------
// NT GEMM: C[m][n] = sum_k A[m][k] * B[n][k] + bias[n]
// A,B bf16; acc fp32; C is OutT (bf16 for intermediate, float for final).
// m97 structure: 128x128 tile, BK=32, 256 thr (4 waves, 2x2 of 64x64),
// 16x16x32 bf16 MFMA, global_load_lds width=16, unpadded [row][k] LDS.
// ---------------------------------------------------------------------------
#define BM 128
#define BN 128
#define BK 32

template <typename OutT>
__global__ __launch_bounds__(256)
void gemm_bt_bias(const bf16* __restrict__ A, const bf16* __restrict__ B,
                  const float* __restrict__ bias, OutT* __restrict__ C,
                  int N, int K) {
    __shared__ bf16 As[BM * BK];
    __shared__ bf16 Bs[BN * BK];

    const int tid  = threadIdx.x;
    const int lane = tid & 63;
    const int wave = tid >> 6;
    const int wm   = (wave >> 1) * 64;   // wave sub-tile row origin
    const int wn   = (wave & 1) * 64;    // wave sub-tile col origin
    const int quad = lane >> 4;          // 0..3
    const int lrow = lane & 15;          // 0..15

    const int bm = blockIdx.x * BM;
    const int bn = blockIdx.y * BN;

    f32x4 acc[4][4] = {};

    // staging: chunk = 16B = 8 bf16. Row of BK=32 bf16 (64B) = 4 chunks.
    // Tile: 128*32*2B = 8KB = 512 chunks -> 2 rounds of 256 threads each.
    for (int kt = 0; kt < K; kt += BK) {
#pragma unroll
        for (int r = 0; r < 2; ++r) {
            const int c   = tid + r * 256;
            const int row = c >> 2;
            const int kc  = (c & 3) * 8;
            GLDS16(A + (long long)(bm + row) * K + (kt + kc), (char*)As + c * 16);
        }
#pragma unroll
        for (int r = 0; r < 2; ++r) {
            const int c   = tid + r * 256;
            const int row = c >> 2;
            const int kc  = (c & 3) * 8;
            GLDS16(B + (long long)(bn + row) * K + (kt + kc), (char*)Bs + c * 16);
        }
        __syncthreads();   // drains vmcnt(0): staging visible

        bf16x8 af[4], bfr[4];
#pragma unroll
        for (int i = 0; i < 4; ++i)
            af[i] = *(const bf16x8*)&As[(wm + i * 16 + lrow) * BK + quad * 8];
#pragma unroll
        for (int j = 0; j < 4; ++j)
            bfr[j] = *(const bf16x8*)&Bs[(wn + j * 16 + lrow) * BK + quad * 8];

#pragma unroll
        for (int i = 0; i < 4; ++i)
#pragma unroll
            for (int j = 0; j < 4; ++j)
                acc[i][j] = __builtin_amdgcn_mfma_f32_16x16x32_bf16(
                    af[i], bfr[j], acc[i][j], 0, 0, 0);

        __syncthreads();   // protect LDS from next iteration's staging
    }

    // epilogue: C/D layout col = lane&15, row = quad*4 + reg  [m89/m91]
#pragma unroll
    for (int j = 0; j < 4; ++j) {
        const int gcol = bn + wn + j * 16 + lrow;
        const float bv = bias[gcol];
#pragma unroll
        for (int i = 0; i < 4; ++i) {
            const int grow0 = bm + wm + i * 16 + quad * 4;
#pragma unroll
            for (int r = 0; r < 4; ++r) {
                const float v = acc[i][j][r] + bv;
                C[(long long)(grow0 + r) * N + gcol] = (OutT)v;
            }
        }
    }
}

// ---------------------------------------------------------------------------
// Causal depthwise conv1d (K=4, left pad 3) + bias + SiLU.
// X,Y: bf16 [b*S + s][c] row-major. conv_w/conv_b: fp32.
// Thread = 8 channels @ one (b,s).
// ---------------------------------------------------------------------------
__global__ __launch_bounds__(256)
void conv_silu_kernel(const bf16* __restrict__ X, const float* __restrict__ cw,
                      const float* __restrict__ cb, bf16* __restrict__ Y) {
    const int gid = blockIdx.x * 256 + threadIdx.x;   // MTOT * 512 threads
    const int c0  = (gid & 511) << 3;                 // channel base (8/thread)
    const int bs  = gid >> 9;
    const int s   = bs & (SEQ - 1);

    // taps: conv_w[c][0][k] fp32 -> per channel one float4
    float w[8][4];
#pragma unroll
    for (int j = 0; j < 8; ++j) {
        const float4 t = *(const float4*)(cw + (long long)(c0 + j) * 4);
        w[j][0] = t.x; w[j][1] = t.y; w[j][2] = t.z; w[j][3] = t.w;
    }
    float acc[8];
    {
        const float4 b0 = *(const float4*)(cb + c0);
        const float4 b1 = *(const float4*)(cb + c0 + 4);
        acc[0] = b0.x; acc[1] = b0.y; acc[2] = b0.z; acc[3] = b0.w;
        acc[4] = b1.x; acc[5] = b1.y; acc[6] = b1.z; acc[7] = b1.w;
    }
#pragma unroll
    for (int k = 0; k < 4; ++k) {
        const int ss = s - 3 + k;
        if (ss >= 0) {
            B8 x;
            x.v = *(const uint4*)(X + (long long)(bs - 3 + k) * CHANNELS + c0);
#pragma unroll
            for (int j = 0; j < 8; ++j) acc[j] += w[j][k] * (float)x.h[j];
        }
    }
    B8 o;
#pragma unroll
    for (int j = 0; j < 8; ++j) {
        const float v = acc[j];
        o.h[j] = (bf16)(v / (1.0f + __expf(-v)));
    }
    *(uint4*)(Y + (long long)bs * CHANNELS + c0) = o.v;
}

// ---------------------------------------------------------------------------
extern "C" void kernel_launch(void* const* d_in, const int* in_sizes, int n_in,
                              void* d_out, int out_size, void* d_ws, size_t ws_size,
                              hipStream_t stream) {
    const float* hs    = (const float*)d_in[0];  // [4,4096,2048]
    const float* w_in  = (const float*)d_in[1];  // [4096,2048]
    const float* b_in  = (const float*)d_in[2];  // [4096]
    const float* cw    = (const float*)d_in[3];  // [4096,1,4]
    const float* cb    = (const float*)d_in[4];  // [4096]
    const float* w_out = (const float*)d_in[5];  // [2048,4096]
    const float* b_out = (const float*)d_in[6];  // [2048]
    float* out = (float*)d_out;                  // [4,4096,2048] fp32

    // ws layout (peak 272 MiB). Y overlaps hs_b/w_in_b — both dead before
    // conv writes Y (stream-ordered).
    char* ws = (char*)d_ws;
    bf16* X       = (bf16*)(ws);                           // [  0,128M)
    bf16* Y       = (bf16*)(ws + ((size_t)128 << 20));     // [128,256M)
    bf16* hs_b    = (bf16*)(ws + ((size_t)128 << 20));     // [128,192M) dies pre-conv
    bf16* w_in_b  = (bf16*)(ws + ((size_t)192 << 20));     // [192,208M) dies pre-conv
    bf16* w_out_b = (bf16*)(ws + ((size_t)256 << 20));     // [256,272M)

    // casts (8 elems/thread, 256 thr/block)
    cast_f32_to_bf16<<<(MTOT * HIDDEN) / (8 * 256), 256, 0, stream>>>(hs, hs_b);
    cast_f32_to_bf16<<<(CHANNELS * HIDDEN) / (8 * 256), 256, 0, stream>>>(w_in, w_in_b);
    cast_f32_to_bf16<<<(HIDDEN * CHANNELS) / (8 * 256), 256, 0, stream>>>(w_out, w_out_b);

    // GEMM1: X = hs @ w_in^T + b_in   [16384 x 4096], K=2048
    dim3 g1(MTOT / BM, CHANNELS / BN);
    gemm_bt_bias<bf16><<<g1, 256, 0, stream>>>(hs_b, w_in_b, b_in, X, CHANNELS, HIDDEN);

    // conv + silu: Y = silu(causal_conv(X) + cb)
    conv_silu_kernel<<<MTOT * (CHANNELS / 8) / 256, 256, 0, stream>>>(X, cw, cb, Y);

    // GEMM2: out = Y @ w_out^T + b_out   [16384 x 2048], K=4096  (fp32 out)
    dim3 g2(MTOT / BM, HIDDEN / BN);
    gemm_bt_bias<float><<<g2, 256, 0, stream>>>(Y, w_out_b, b_out, out, HIDDEN, CHANNELS);
}

// Round 4
// 1242.723 us; speedup vs baseline: 1.0880x; 1.0880x over previous
//
#include <hip/hip_runtime.h>
#include <hip/hip_bf16.h>
#include <stdint.h>

#define SEQ      4096
#define BATCH    4
#define HIDDEN   2048
#define CHANNELS 4096
#define MTOT     (BATCH*SEQ)   // 16384

typedef __bf16 bf16;
typedef __bf16 bf16x8 __attribute__((ext_vector_type(8)));
typedef float  f32x4  __attribute__((ext_vector_type(4)));

// async 16B global->LDS (wave-uniform base + lane*16 on LDS side)
#define GLDS16(g, l) __builtin_amdgcn_global_load_lds(                      \
    (const __attribute__((address_space(1))) void*)(g),                     \
    (__attribute__((address_space(3))) void*)(l), 16, 0, 0)

// ---------------------------------------------------------------------------
// fp32 -> bf16 cast, 8 elems/thread
// ---------------------------------------------------------------------------
union B8 { uint4 v; bf16 h[8]; };

__global__ __launch_bounds__(256)
void cast_f32_to_bf16(const float* __restrict__ in, bf16* __restrict__ out) {
    const long long i = (long long)blockIdx.x * 256 + threadIdx.x;
    const float4 a = ((const float4*)in)[2 * i];
    const float4 b = ((const float4*)in)[2 * i + 1];
    B8 o;
    o.h[0] = (bf16)a.x; o.h[1] = (bf16)a.y; o.h[2] = (bf16)a.z; o.h[3] = (bf16)a.w;
    o.h[4] = (bf16)b.x; o.h[5] = (bf16)b.y; o.h[6] = (bf16)b.z; o.h[7] = (bf16)b.w;
    *(uint4*)(out + 8 * i) = o.v;
}

// ---------------------------------------------------------------------------
// NT GEMM: C[m][n] = sum_k A[m][k]*B[n][k] + bias[n]
// 128x128 tile, BK=64, 256 thr (4 waves, 2x2 of 64x64), 16x16x32 bf16 MFMA.
// LDS: [row][chunk] where 16B chunk at slot q holds global chunk q^(row&7)
// (XOR swizzle -> conflict-free ds_read_b128; GLDS dest stays lane-linear).
// K, N compile-time.
// ---------------------------------------------------------------------------
#define BM 128
#define BN 128
#define BK 64   // 8 chunks of 8 bf16 per row; row = 128 B

template <typename OutT, int N, int K>
__global__ __launch_bounds__(256)
void gemm_bt_bias(const bf16* __restrict__ A, const bf16* __restrict__ B,
                  const float* __restrict__ bias, OutT* __restrict__ C) {
    __shared__ bf16 As[BM * BK];   // 16 KB
    __shared__ bf16 Bs[BN * BK];   // 16 KB

    const int tid  = threadIdx.x;
    const int lane = tid & 63;
    const int wave = tid >> 6;
    const int wm   = (wave >> 1) * 64;   // wave sub-tile row origin
    const int wn   = (wave & 1) * 64;    // wave sub-tile col origin
    const int quad = lane >> 4;          // 0..3
    const int lrow = lane & 15;          // 0..15

    const int bm = blockIdx.x * BM;
    const int bn = blockIdx.y * BN;

    f32x4 acc[4][4] = {};

    // staging: tile = 128 rows x 8 chunks (16B) = 1024 chunks -> 4 rounds.
    // thread round-chunk c: row=c>>3, slot q=c&7; fetch global chunk q^(row&7).
    for (int kt = 0; kt < K; kt += BK) {
#pragma unroll
        for (int r = 0; r < 4; ++r) {
            const int c   = tid + r * 256;
            const int row = c >> 3;
            const int qg  = (c & 7) ^ (row & 7);
            GLDS16(A + (long long)(bm + row) * K + (kt + qg * 8), (char*)As + c * 16);
        }
#pragma unroll
        for (int r = 0; r < 4; ++r) {
            const int c   = tid + r * 256;
            const int row = c >> 3;
            const int qg  = (c & 7) ^ (row & 7);
            GLDS16(B + (long long)(bn + row) * K + (kt + qg * 8), (char*)Bs + c * 16);
        }
        __syncthreads();   // drains vmcnt(0): staging visible

        // two k=32 halves per staging round
#pragma unroll
        for (int h = 0; h < 2; ++h) {
            bf16x8 af[4], bfr[4];
#pragma unroll
            for (int i = 0; i < 4; ++i) {
                const int rr = wm + i * 16 + lrow;
                const int sl = (h * 4 + quad) ^ (rr & 7);
                af[i] = *(const bf16x8*)&As[rr * BK + sl * 8];
            }
#pragma unroll
            for (int j = 0; j < 4; ++j) {
                const int rr = wn + j * 16 + lrow;
                const int sl = (h * 4 + quad) ^ (rr & 7);
                bfr[j] = *(const bf16x8*)&Bs[rr * BK + sl * 8];
            }
#pragma unroll
            for (int i = 0; i < 4; ++i)
#pragma unroll
                for (int j = 0; j < 4; ++j)
                    acc[i][j] = __builtin_amdgcn_mfma_f32_16x16x32_bf16(
                        af[i], bfr[j], acc[i][j], 0, 0, 0);
        }

        __syncthreads();   // protect LDS from next iteration's staging
    }

    // epilogue: C/D layout col = lane&15, row = quad*4 + reg  [m89/m91]
#pragma unroll
    for (int j = 0; j < 4; ++j) {
        const int gcol = bn + wn + j * 16 + lrow;
        const float bv = bias[gcol];
#pragma unroll
        for (int i = 0; i < 4; ++i) {
            const int grow0 = bm + wm + i * 16 + quad * 4;
#pragma unroll
            for (int r = 0; r < 4; ++r) {
                const float v = acc[i][j][r] + bv;
                C[(long long)(grow0 + r) * N + gcol] = (OutT)v;
            }
        }
    }
}

// ---------------------------------------------------------------------------
// Causal depthwise conv1d (K=4, left pad 3) + bias + SiLU.
// X,Y: bf16 [b*S + s][c] row-major. conv_w/conv_b: fp32.
// ---------------------------------------------------------------------------
__global__ __launch_bounds__(256)
void conv_silu_kernel(const bf16* __restrict__ X, const float* __restrict__ cw,
                      const float* __restrict__ cb, bf16* __restrict__ Y) {
    const int gid = blockIdx.x * 256 + threadIdx.x;   // MTOT * 512 threads
    const int c0  = (gid & 511) << 3;                 // channel base (8/thread)
    const int bs  = gid >> 9;
    const int s   = bs & (SEQ - 1);

    float w[8][4];
#pragma unroll
    for (int j = 0; j < 8; ++j) {
        const float4 t = *(const float4*)(cw + (long long)(c0 + j) * 4);
        w[j][0] = t.x; w[j][1] = t.y; w[j][2] = t.z; w[j][3] = t.w;
    }
    float acc[8];
    {
        const float4 b0 = *(const float4*)(cb + c0);
        const float4 b1 = *(const float4*)(cb + c0 + 4);
        acc[0] = b0.x; acc[1] = b0.y; acc[2] = b0.z; acc[3] = b0.w;
        acc[4] = b1.x; acc[5] = b1.y; acc[6] = b1.z; acc[7] = b1.w;
    }
#pragma unroll
    for (int k = 0; k < 4; ++k) {
        const int ss = s - 3 + k;
        if (ss >= 0) {
            B8 x;
            x.v = *(const uint4*)(X + (long long)(bs - 3 + k) * CHANNELS + c0);
#pragma unroll
            for (int j = 0; j < 8; ++j) acc[j] += w[j][k] * (float)x.h[j];
        }
    }
    B8 o;
#pragma unroll
    for (int j = 0; j < 8; ++j) {
        const float v = acc[j];
        o.h[j] = (bf16)(v / (1.0f + __expf(-v)));
    }
    *(uint4*)(Y + (long long)bs * CHANNELS + c0) = o.v;
}

// ---------------------------------------------------------------------------
extern "C" void kernel_launch(void* const* d_in, const int* in_sizes, int n_in,
                              void* d_out, int out_size, void* d_ws, size_t ws_size,
                              hipStream_t stream) {
    const float* hs    = (const float*)d_in[0];  // [4,4096,2048]
    const float* w_in  = (const float*)d_in[1];  // [4096,2048]
    const float* b_in  = (const float*)d_in[2];  // [4096]
    const float* cw    = (const float*)d_in[3];  // [4096,1,4]
    const float* cb    = (const float*)d_in[4];  // [4096]
    const float* w_out = (const float*)d_in[5];  // [2048,4096]
    const float* b_out = (const float*)d_in[6];  // [2048]
    float* out = (float*)d_out;                  // [4,4096,2048] fp32

    // ws layout (peak 272 MiB). Y overlaps hs_b/w_in_b — both dead before
    // conv writes Y (stream-ordered).
    char* ws = (char*)d_ws;
    bf16* X       = (bf16*)(ws);                           // [  0,128M)
    bf16* Y       = (bf16*)(ws + ((size_t)128 << 20));     // [128,256M)
    bf16* hs_b    = (bf16*)(ws + ((size_t)128 << 20));     // [128,192M) dies pre-conv
    bf16* w_in_b  = (bf16*)(ws + ((size_t)192 << 20));     // [192,208M) dies pre-conv
    bf16* w_out_b = (bf16*)(ws + ((size_t)256 << 20));     // [256,272M)

    cast_f32_to_bf16<<<(MTOT * HIDDEN) / (8 * 256), 256, 0, stream>>>(hs, hs_b);
    cast_f32_to_bf16<<<(CHANNELS * HIDDEN) / (8 * 256), 256, 0, stream>>>(w_in, w_in_b);
    cast_f32_to_bf16<<<(HIDDEN * CHANNELS) / (8 * 256), 256, 0, stream>>>(w_out, w_out_b);

    // GEMM1: X = hs @ w_in^T + b_in   [16384 x 4096], K=2048
    dim3 g1(MTOT / BM, CHANNELS / BN);
    gemm_bt_bias<bf16, CHANNELS, HIDDEN><<<g1, 256, 0, stream>>>(hs_b, w_in_b, b_in, X);

    // conv + silu: Y = silu(causal_conv(X) + cb)
    conv_silu_kernel<<<MTOT * (CHANNELS / 8) / 256, 256, 0, stream>>>(X, cw, cb, Y);

    // GEMM2: out = Y @ w_out^T + b_out   [16384 x 2048], K=4096  (fp32 out)
    dim3 g2(MTOT / BM, HIDDEN / BN);
    gemm_bt_bias<float, HIDDEN, CHANNELS><<<g2, 256, 0, stream>>>(Y, w_out_b, b_out, out);
}